// Round 3
// baseline (1443.236 us; speedup 1.0000x reference)
//
#include <hip/hip_runtime.h>
#include <stdint.h>

typedef unsigned short u16;
typedef __attribute__((ext_vector_type(4))) float f32x4;
typedef __attribute__((ext_vector_type(8))) short bf16x8;
typedef __attribute__((ext_vector_type(4))) unsigned short u16x4;

#define S_LEN 1024
#define NROWS 2048   // B*S
#define FFN   2048
#define VOCAB 32000

__device__ __forceinline__ u16 f2bf(float f) {
  union { float f; uint32_t u; } v; v.f = f;
  uint32_t r = v.u + 0x7fffu + ((v.u >> 16) & 1u);
  return (u16)(r >> 16);
}
__device__ __forceinline__ float bf2fl(u16 b) {
  union { uint32_t u; float f; } x; x.u = ((uint32_t)b) << 16; return x.f;
}
__device__ __forceinline__ void split2(float v, u16& h, u16& l) {
  h = f2bf(v); l = f2bf(v - bf2fl(h));
}

#define MFMA16(a, b, c) __builtin_amdgcn_mfma_f32_16x16x32_bf16((a), (b), (c), 0, 0, 0)

__device__ __forceinline__ void gload16(const u16* g, u16* l) {
  __builtin_amdgcn_global_load_lds((const __attribute__((address_space(1))) uint32_t*)g,
                                   (__attribute__((address_space(3))) uint32_t*)l, 16, 0, 0);
}

// ------- split-precision 128x128 K-step-32 core: C = (AH+AL) @ (BH+BL)^T, 3-term --------
// LDS layout (u16 units): AH tile [0,4096), AL [4096,8192), BH [8192,12288), BL [12288,16384)
__device__ __forceinline__ void gemm_core_split(const u16* __restrict__ AH, const u16* __restrict__ AL,
                                                const u16* __restrict__ BH, const u16* __restrict__ BL,
                                                int K, u16* S, f32x4 acc[4][4]) {
  const int tid = threadIdx.x, lane = tid & 63, w = tid >> 6;
  const int rBase = blockIdx.y * 128, cBase = blockIdx.x * 128;
  const int lrow = tid >> 2, lc8 = (tid & 3) * 8;
  const size_t rowA = (size_t)(rBase + lrow) * K + lc8;
  const size_t rowB = (size_t)(cBase + lrow) * K + lc8;
  const size_t half = (size_t)64 * K;
  u16* dst = S + w * 512;               // wave-uniform base; HW adds lane*16B
  const int wr = (w >> 1) * 64, wc = (w & 1) * 64;
  const int fr = lane & 15, fg = lane >> 4;
  for (int k0 = 0; k0 < K; k0 += 32) {
    gload16(AH + rowA + k0, dst);
    gload16(AH + rowA + half + k0, dst + 2048);
    gload16(AL + rowA + k0, dst + 4096);
    gload16(AL + rowA + half + k0, dst + 6144);
    gload16(BH + rowB + k0, dst + 8192);
    gload16(BH + rowB + half + k0, dst + 10240);
    gload16(BL + rowB + k0, dst + 12288);
    gload16(BL + rowB + half + k0, dst + 14336);
    __syncthreads();   // drains vmcnt before reads
    bf16x8 ah[4], al[4], bh[4], bl[4];
#pragma unroll
    for (int mi = 0; mi < 4; mi++) {
      int o = (wr + mi * 16 + fr) * 32 + fg * 8;
      ah[mi] = *(const bf16x8*)(S + o);
      al[mi] = *(const bf16x8*)(S + 4096 + o);
    }
#pragma unroll
    for (int ni = 0; ni < 4; ni++) {
      int o = (wc + ni * 16 + fr) * 32 + fg * 8;
      bh[ni] = *(const bf16x8*)(S + 8192 + o);
      bl[ni] = *(const bf16x8*)(S + 12288 + o);
    }
#pragma unroll
    for (int mi = 0; mi < 4; mi++)
#pragma unroll
      for (int ni = 0; ni < 4; ni++) {
        acc[mi][ni] = MFMA16(ah[mi], bh[ni], acc[mi][ni]);
        acc[mi][ni] = MFMA16(ah[mi], bl[ni], acc[mi][ni]);
        acc[mi][ni] = MFMA16(al[mi], bh[ni], acc[mi][ni]);
      }
    __syncthreads();   // protect LDS from next-iteration staging
  }
}

// ------- generic split GEMM (+bias)(relu); outputs f32 and/or split-bf16 -----------------
template<bool RELU>
__global__ __launch_bounds__(256) void gemm_bt(const u16* __restrict__ AH, const u16* __restrict__ AL,
                                               const u16* __restrict__ BH, const u16* __restrict__ BL,
                                               const float* __restrict__ bias,
                                               float* __restrict__ outF,
                                               u16* __restrict__ outBH, u16* __restrict__ outBL,
                                               int K, int N) {
  __shared__ u16 S[16384];
  f32x4 acc[4][4] = {};
  gemm_core_split(AH, AL, BH, BL, K, S, acc);
  const int lane = threadIdx.x & 63, w = threadIdx.x >> 6;
  const int wr = (w >> 1) * 64, wc = (w & 1) * 64;
  const int fr = lane & 15, fg = lane >> 4;
  const int rBase = blockIdx.y * 128, cBase = blockIdx.x * 128;
#pragma unroll
  for (int ni = 0; ni < 4; ni++) {
    int col = cBase + wc + ni * 16 + fr;
    float bv = bias ? bias[col] : 0.f;
#pragma unroll
    for (int mi = 0; mi < 4; mi++) {
      int row0 = rBase + wr + mi * 16 + fg * 4;
#pragma unroll
      for (int i = 0; i < 4; i++) {
        float v = acc[mi][ni][i] + bv;
        if (RELU) v = fmaxf(v, 0.f);
        size_t idx = (size_t)(row0 + i) * N + col;
        if (outF) outF[idx] = v;
        if (outBH) { u16 h, l; split2(v, h, l); outBH[idx] = h; outBL[idx] = l; }
      }
    }
  }
}

// ------- fused QKV GEMM: z=0 Q (scaled, split), z=1 K (split), z=2 V (transposed bf16) ---
__global__ __launch_bounds__(256) void gemm_qkv(const u16* __restrict__ AH, const u16* __restrict__ AL,
                                                const u16* __restrict__ WqH, const u16* __restrict__ WqL,
                                                const u16* __restrict__ WkH, const u16* __restrict__ WkL,
                                                const u16* __restrict__ WvH, const u16* __restrict__ WvL,
                                                u16* __restrict__ QoH, u16* __restrict__ QoL,
                                                u16* __restrict__ KoH, u16* __restrict__ KoL,
                                                u16* __restrict__ VTo) {
  __shared__ u16 S[16384];
  const int z = blockIdx.z;
  const u16* BH = (z == 0) ? WqH : (z == 1) ? WkH : WvH;
  const u16* BL = (z == 0) ? WqL : (z == 1) ? WkL : WvL;
  f32x4 acc[4][4] = {};
  gemm_core_split(AH, AL, BH, BL, 512, S, acc);
  const int lane = threadIdx.x & 63, w = threadIdx.x >> 6;
  const int wr = (w >> 1) * 64, wc = (w & 1) * 64;
  const int fr = lane & 15, fg = lane >> 4;
  const int rBase = blockIdx.y * 128, cBase = blockIdx.x * 128;
  if (z == 2) {
    // VT[((b*8+h)*64 + d)*1024 + s]  (single bf16 is enough for V)
#pragma unroll
    for (int ni = 0; ni < 4; ni++) {
      int col = cBase + wc + ni * 16 + fr;
      int h = col >> 6, d = col & 63;
#pragma unroll
      for (int mi = 0; mi < 4; mi++) {
        int row0 = rBase + wr + mi * 16 + fg * 4;
        int b = row0 >> 10, s0 = row0 & 1023;
        u16x4 pk;
#pragma unroll
        for (int i = 0; i < 4; i++) pk[i] = f2bf(acc[mi][ni][i]);
        *(u16x4*)(VTo + (((size_t)(b * 8 + h) * 64 + d) << 10) + s0) = pk;
      }
    }
  } else {
    u16* OH = (z == 0) ? QoH : KoH;
    u16* OL = (z == 0) ? QoL : KoL;
    const float sc = (z == 0) ? 0.125f : 1.0f;   // fold 1/sqrt(64) into Q
#pragma unroll
    for (int ni = 0; ni < 4; ni++) {
      int col = cBase + wc + ni * 16 + fr;
#pragma unroll
      for (int mi = 0; mi < 4; mi++) {
        int row0 = rBase + wr + mi * 16 + fg * 4;
#pragma unroll
        for (int i = 0; i < 4; i++) {
          size_t idx = (size_t)(row0 + i) * 512 + col;
          u16 h, l; split2(acc[mi][ni][i] * sc, h, l);
          OH[idx] = h; OL[idx] = l;
        }
      }
    }
  }
}

// ------- windowed-causal flash attention, split-precision scores -------------------------
__global__ __launch_bounds__(256) void attn_win(const u16* __restrict__ QH, const u16* __restrict__ QL,
                                                const u16* __restrict__ KHp_, const u16* __restrict__ KLp_,
                                                const u16* __restrict__ VT,
                                                u16* __restrict__ ctxH, u16* __restrict__ ctxL, int win) {
  const int bh = blockIdx.x, b = bh >> 3, h = bh & 7;
  const int lane = threadIdx.x & 63, w = threadIdx.x >> 6;
  const int q0 = (blockIdx.y * 4 + w) * 16;
  const int qi = lane & 15, g = lane >> 4;
  const size_t hoff = (size_t)b * 1024 * 512 + h * 64;
  const u16* QHp = QH + hoff;  const u16* QLp = QL + hoff;
  const u16* KHb = KHp_ + hoff; const u16* KLb = KLp_ + hoff;
  const u16* Vp = VT + ((size_t)bh * 64) * 1024;
  const size_t qrow = (size_t)(q0 + qi) * 512;
  const bf16x8 qH0 = *(const bf16x8*)(QHp + qrow + g * 8);
  const bf16x8 qH1 = *(const bf16x8*)(QHp + qrow + 32 + g * 8);
  const bf16x8 qL0 = *(const bf16x8*)(QLp + qrow + g * 8);
  const bf16x8 qL1 = *(const bf16x8*)(QLp + qrow + 32 + g * 8);
  const int q = q0 + qi;
  float mrun = -1e30f, lrun = 0.f;
  f32x4 acc[4] = {};
  int jStart = q0 - win; if (jStart < 0) jStart = 0; jStart &= ~31;
  const int srcA = ((g & 1) * 2) * 16 + qi, srcB = srcA + 16;
  const bool hisel = (g & 2) != 0;
  for (int j0 = jStart; j0 <= q0 + 15; j0 += 32) {   // j0 32-aligned => j0 <= 992, no OOB
    const size_t rlo = (size_t)(j0 + qi) * 512, rhi = (size_t)(j0 + 16 + qi) * 512;
    bf16x8 aH0 = *(const bf16x8*)(KHb + rlo + g * 8);
    bf16x8 aH1 = *(const bf16x8*)(KHb + rlo + 32 + g * 8);
    bf16x8 aL0 = *(const bf16x8*)(KLb + rlo + g * 8);
    bf16x8 aL1 = *(const bf16x8*)(KLb + rlo + 32 + g * 8);
    bf16x8 cH0 = *(const bf16x8*)(KHb + rhi + g * 8);
    bf16x8 cH1 = *(const bf16x8*)(KHb + rhi + 32 + g * 8);
    bf16x8 cL0 = *(const bf16x8*)(KLb + rhi + g * 8);
    bf16x8 cL1 = *(const bf16x8*)(KLb + rhi + 32 + g * 8);
    f32x4 slo = {0.f, 0.f, 0.f, 0.f}, shi = {0.f, 0.f, 0.f, 0.f};
    slo = MFMA16(aH0, qH0, slo); slo = MFMA16(aH1, qH1, slo);
    slo = MFMA16(aH0, qL0, slo); slo = MFMA16(aH1, qL1, slo);
    slo = MFMA16(aL0, qH0, slo); slo = MFMA16(aL1, qH1, slo);
    shi = MFMA16(cH0, qH0, shi); shi = MFMA16(cH1, qH1, shi);
    shi = MFMA16(cH0, qL0, shi); shi = MFMA16(cH1, qL1, shi);
    shi = MFMA16(cL0, qH0, shi); shi = MFMA16(cL1, qH1, shi);
    float t[8];
#pragma unroll
    for (int i = 0; i < 4; i++) {
      int keyL = j0 + g * 4 + i, keyH = keyL + 16;
      t[i]     = (keyL <= q && q - keyL <= win) ? slo[i] : -1e30f;
      t[4 + i] = (keyH <= q && q - keyH <= win) ? shi[i] : -1e30f;
    }
    float tmax = t[0];
#pragma unroll
    for (int j = 1; j < 8; j++) tmax = fmaxf(tmax, t[j]);
    tmax = fmaxf(tmax, __shfl_xor(tmax, 16));
    tmax = fmaxf(tmax, __shfl_xor(tmax, 32));
    const float mnew = fmaxf(mrun, tmax);
    const float scl = __expf(mrun - mnew);
    // redistribute into B-operand order: lane(g,qi) elem j holds key j0+g*8+j
    float p[8]; float rsum = 0.f;
#pragma unroll
    for (int j = 0; j < 4; j++) {
      float aLo = __shfl(t[j], srcA), aHi = __shfl(t[4 + j], srcA);
      float bLo = __shfl(t[j], srcB), bHi = __shfl(t[4 + j], srcB);
      float tA = hisel ? aHi : aLo;
      float tB = hisel ? bHi : bLo;
      int keyA = j0 + g * 8 + j, keyB = keyA + 4;
      float pA = (keyA <= q && q - keyA <= win) ? __expf(tA - mnew) : 0.f;
      float pB = (keyB <= q && q - keyB <= win) ? __expf(tB - mnew) : 0.f;
      p[j] = pA; p[4 + j] = pB;
      rsum += pA + pB;
    }
    rsum += __shfl_xor(rsum, 16);
    rsum += __shfl_xor(rsum, 32);
    lrun = lrun * scl + rsum;
    mrun = mnew;
    bf16x8 pf;
#pragma unroll
    for (int j = 0; j < 8; j++) pf[j] = (short)f2bf(p[j]);
#pragma unroll
    for (int n = 0; n < 4; n++) {
      acc[n] *= scl;
      bf16x8 vf = *(const bf16x8*)(Vp + (size_t)(n * 16 + qi) * 1024 + j0 + g * 8);
      acc[n] = MFMA16(vf, pf, acc[n]);
    }
  }
  const float inv = 1.f / lrun;
  const size_t co = (size_t)(b * 1024 + q) * 512 + h * 64;
#pragma unroll
  for (int n = 0; n < 4; n++) {
    u16x4 ph, pl;
#pragma unroll
    for (int i = 0; i < 4; i++) { u16 hh, ll; split2(acc[n][i] * inv, hh, ll); ph[i] = hh; pl[i] = ll; }
    *(u16x4*)(ctxH + co + n * 16 + g * 4) = ph;
    *(u16x4*)(ctxL + co + n * 16 + g * 4) = pl;
  }
}

// ------- LayerNorm + residual: out = res[row&mask] + LN(in)*scale + bias -----------------
// NOTE: in and outF may alias (same rows, read-before-write per thread) — no restrict.
__global__ __launch_bounds__(256) void ln_res(const float* in, const float* res,
                                              const float* bias, const float* scale,
                                              float* outF, u16* outH, u16* outL, int resMask) {
  const int row = blockIdx.x * 4 + (threadIdx.x >> 6);
  const int lane = threadIdx.x & 63;
  const float* ip = in + (size_t)row * 512 + lane * 8;
  f32x4 a = *(const f32x4*)ip, c = *(const f32x4*)(ip + 4);
  float s = a[0] + a[1] + a[2] + a[3] + c[0] + c[1] + c[2] + c[3];
  float s2 = a[0]*a[0] + a[1]*a[1] + a[2]*a[2] + a[3]*a[3]
           + c[0]*c[0] + c[1]*c[1] + c[2]*c[2] + c[3]*c[3];
#pragma unroll
  for (int m = 1; m < 64; m <<= 1) { s += __shfl_xor(s, m); s2 += __shfl_xor(s2, m); }
  const float mean = s * (1.f / 512.f);
  float var = s2 * (1.f / 512.f) - mean * mean;
  var = fmaxf(var, 0.f);
  const float rstd = rsqrtf(var + 1e-6f);
  const int cidx = lane * 8;
  const float* rp = res + (size_t)(row & resMask) * 512 + cidx;
  f32x4 r0 = *(const f32x4*)rp, r1 = *(const f32x4*)(rp + 4);
  f32x4 sc0 = *(const f32x4*)(scale + cidx), sc1 = *(const f32x4*)(scale + cidx + 4);
  f32x4 b0 = *(const f32x4*)(bias + cidx), b1 = *(const f32x4*)(bias + cidx + 4);
  f32x4 o0, o1;
#pragma unroll
  for (int i = 0; i < 4; i++) {
    o0[i] = r0[i] + (a[i] - mean) * rstd * sc0[i] + b0[i];
    o1[i] = r1[i] + (c[i] - mean) * rstd * sc1[i] + b1[i];
  }
  if (outF) {
    *(f32x4*)(outF + (size_t)row * 512 + cidx) = o0;
    *(f32x4*)(outF + (size_t)row * 512 + cidx + 4) = o1;
  }
  if (outH) {
    u16x4 h0, h1, l0, l1;
#pragma unroll
    for (int i = 0; i < 4; i++) {
      u16 hh, ll;
      split2(o0[i], hh, ll); h0[i] = hh; l0[i] = ll;
      split2(o1[i], hh, ll); h1[i] = hh; l1[i] = ll;
    }
    *(u16x4*)(outH + (size_t)row * 512 + cidx) = h0;
    *(u16x4*)(outH + (size_t)row * 512 + cidx + 4) = h1;
    *(u16x4*)(outL + (size_t)row * 512 + cidx) = l0;
    *(u16x4*)(outL + (size_t)row * 512 + cidx + 4) = l1;
  }
}

// ------- embedding gather + split-bf16 convert ------------------------------------------
__global__ void emb_gather(const int* __restrict__ idx, const float* __restrict__ emb,
                           u16* __restrict__ outH, u16* __restrict__ outL) {
  const int t = blockIdx.x * 256 + threadIdx.x;  // 2048 rows * 16 threads
  const int r = t >> 4, e = (t & 15) * 8;
  const int id = idx[r];
  const float* p = emb + (size_t)id * 128 + e;
  f32x4 a = *(const f32x4*)p, b = *(const f32x4*)(p + 4);
  u16x4 ha, hb, la, lb;
#pragma unroll
  for (int i = 0; i < 4; i++) {
    u16 hh, ll;
    split2(a[i], hh, ll); ha[i] = hh; la[i] = ll;
    split2(b[i], hh, ll); hb[i] = hh; lb[i] = ll;
  }
  *(u16x4*)(outH + (size_t)r * 128 + e) = ha;
  *(u16x4*)(outH + (size_t)r * 128 + e + 4) = hb;
  *(u16x4*)(outL + (size_t)r * 128 + e) = la;
  *(u16x4*)(outL + (size_t)r * 128 + e + 4) = lb;
}

// ------- transpose-convert weights to split-bf16: Wt[n][k] = W[k][n] ---------------------
__global__ void wtrans(const float* __restrict__ W, u16* __restrict__ WtH, u16* __restrict__ WtL,
                       int K, int N) {
  __shared__ float tile[32][33];
  const size_t zo = (size_t)blockIdx.z * K * N;
  const float* Wp = W + zo;
  const int n0 = blockIdx.x * 32, k0 = blockIdx.y * 32;
  const int tx = threadIdx.x, ty = threadIdx.y;
#pragma unroll
  for (int i = 0; i < 4; i++)
    tile[ty + 8 * i][tx] = Wp[(size_t)(k0 + ty + 8 * i) * N + n0 + tx];
  __syncthreads();
#pragma unroll
  for (int i = 0; i < 4; i++) {
    float v = tile[tx][ty + 8 * i];
    u16 hh, ll; split2(v, hh, ll);
    size_t o = zo + (size_t)(n0 + ty + 8 * i) * K + k0 + tx;
    WtH[o] = hh; WtL[o] = ll;
  }
}

extern "C" void kernel_launch(void* const* d_in, const int* in_sizes, int n_in,
                              void* d_out, int out_size, void* d_ws, size_t ws_size,
                              hipStream_t stream) {
  (void)in_sizes; (void)n_in; (void)out_size; (void)ws_size;
  const int*   x_input   = (const int*)d_in[0];
  const float* W_emb     = (const float*)d_in[1];
  const float* W_dec_lin = (const float*)d_in[2];
  const float* p_decoder = (const float*)d_in[3];
  const float* p_q       = (const float*)d_in[4];
  const float* p_k       = (const float*)d_in[5];
  const float* p_v       = (const float*)d_in[6];
  const float* p_c       = (const float*)d_in[7];
  const float* p_ff1     = (const float*)d_in[8];
  const float* p_ff2     = (const float*)d_in[9];
  const float* b_ff1     = (const float*)d_in[10];
  const float* b_ff2     = (const float*)d_in[11];
  const float* b_bias_i  = (const float*)d_in[12];
  const float* b_scale_i = (const float*)d_in[13];
  const float* b_bias_1  = (const float*)d_in[14];
  const float* b_scale_1 = (const float*)d_in[15];
  const float* b_bias_2  = (const float*)d_in[16];
  const float* b_scale_2 = (const float*)d_in[17];
  const float* d_o_bias  = (const float*)d_in[18];
  const float* d_o_scale = (const float*)d_in[19];
  const float* x_pos     = (const float*)d_in[20];
  float* out = (float*)d_out;

  char* base = (char*)d_ws; size_t off = 0;
  auto alloc = [&](size_t bytes) -> void* {
    off = (off + 255) & ~(size_t)255;
    void* p = base + off; off += bytes; return p;
  };
  const size_t SQ = (size_t)512 * 512 * 2;        // bytes of one 512x512 bf16 matrix
  u16* WdecH = (u16*)alloc((size_t)512 * 128 * 2);
  u16* WdecL = (u16*)alloc((size_t)512 * 128 * 2);
  u16* WqH = (u16*)alloc(4 * SQ); u16* WqL = (u16*)alloc(4 * SQ);
  u16* WkH = (u16*)alloc(4 * SQ); u16* WkL = (u16*)alloc(4 * SQ);
  u16* WvH = (u16*)alloc(4 * SQ); u16* WvL = (u16*)alloc(4 * SQ);
  u16* WcH = (u16*)alloc(4 * SQ); u16* WcL = (u16*)alloc(4 * SQ);
  u16* Wff1H = (u16*)alloc((size_t)4 * FFN * 512 * 2);
  u16* Wff1L = (u16*)alloc((size_t)4 * FFN * 512 * 2);
  u16* Wff2H = (u16*)alloc((size_t)4 * 512 * FFN * 2);
  u16* Wff2L = (u16*)alloc((size_t)4 * 512 * FFN * 2);
  u16* WoutH = (u16*)alloc((size_t)VOCAB * 512 * 2);
  u16* WoutL = (u16*)alloc((size_t)VOCAB * 512 * 2);
  u16* AembH = (u16*)alloc((size_t)NROWS * 128 * 2);
  u16* AembL = (u16*)alloc((size_t)NROWS * 128 * 2);
  float* decIn    = (float*)alloc((size_t)NROWS * 512 * 4);
  float* layerInF = (float*)alloc((size_t)NROWS * 512 * 4);
  u16* layerInH = (u16*)alloc((size_t)NROWS * 512 * 2);
  u16* layerInL = (u16*)alloc((size_t)NROWS * 512 * 2);
  u16* QbH = (u16*)alloc((size_t)NROWS * 512 * 2);
  u16* QbL = (u16*)alloc((size_t)NROWS * 512 * 2);
  u16* KbH = (u16*)alloc((size_t)NROWS * 512 * 2);
  u16* KbL = (u16*)alloc((size_t)NROWS * 512 * 2);
  u16* VTb = (u16*)alloc((size_t)NROWS * 512 * 2);
  u16* ctxHb = (u16*)alloc((size_t)NROWS * 512 * 2);
  u16* ctxLb = (u16*)alloc((size_t)NROWS * 512 * 2);
  float* attnOutF = (float*)alloc((size_t)NROWS * 512 * 4);  // reused as ffwF
  float* x1F = (float*)alloc((size_t)NROWS * 512 * 4);
  u16* x1H = (u16*)alloc((size_t)NROWS * 512 * 2);
  u16* x1L = (u16*)alloc((size_t)NROWS * 512 * 2);
  u16* hBH = (u16*)alloc((size_t)NROWS * FFN * 2);
  u16* hBL = (u16*)alloc((size_t)NROWS * FFN * 2);
  u16* decOutH = (u16*)alloc((size_t)NROWS * 512 * 2);
  u16* decOutL = (u16*)alloc((size_t)NROWS * 512 * 2);

  const dim3 tb(32, 8, 1);
  wtrans<<<dim3(16, 4, 1), tb, 0, stream>>>(W_dec_lin, WdecH, WdecL, 128, 512);
  wtrans<<<dim3(16, 16, 4), tb, 0, stream>>>(p_q, WqH, WqL, 512, 512);
  wtrans<<<dim3(16, 16, 4), tb, 0, stream>>>(p_k, WkH, WkL, 512, 512);
  wtrans<<<dim3(16, 16, 4), tb, 0, stream>>>(p_v, WvH, WvL, 512, 512);
  wtrans<<<dim3(16, 16, 4), tb, 0, stream>>>(p_c, WcH, WcL, 512, 512);
  wtrans<<<dim3(FFN / 32, 16, 4), tb, 0, stream>>>(p_ff1, Wff1H, Wff1L, 512, FFN);
  wtrans<<<dim3(16, FFN / 32, 4), tb, 0, stream>>>(p_ff2, Wff2H, Wff2L, FFN, 512);
  wtrans<<<dim3(VOCAB / 32, 16, 1), tb, 0, stream>>>(p_decoder, WoutH, WoutL, 512, VOCAB);

  emb_gather<<<dim3(128), 256, 0, stream>>>(x_input, W_emb, AembH, AembL);
  gemm_bt<false><<<dim3(4, 16), 256, 0, stream>>>(AembH, AembL, WdecH, WdecL, nullptr,
                                                  decIn, nullptr, nullptr, 128, 512);

  const int wins[4] = {256, 341, 512, 1024};
  const float* curX = decIn;
  for (int m = 0; m < 4; m++) {
    const size_t o = (size_t)m * 512 * 512;
    const size_t of = (size_t)m * FFN * 512;
    ln_res<<<dim3(512), 256, 0, stream>>>(curX, x_pos + (size_t)m * S_LEN * 512,
                                          b_bias_i + m * 512, b_scale_i + m * 512,
                                          layerInF, layerInH, layerInL, 1023);
    gemm_qkv<<<dim3(4, 16, 3), 256, 0, stream>>>(layerInH, layerInL,
                                                 WqH + o, WqL + o, WkH + o, WkL + o,
                                                 WvH + o, WvL + o,
                                                 QbH, QbL, KbH, KbL, VTb);
    attn_win<<<dim3(16, 16), 256, 0, stream>>>(QbH, QbL, KbH, KbL, VTb, ctxHb, ctxLb, wins[m]);
    gemm_bt<false><<<dim3(4, 16), 256, 0, stream>>>(ctxHb, ctxLb, WcH + o, WcL + o, nullptr,
                                                    attnOutF, nullptr, nullptr, 512, 512);
    ln_res<<<dim3(512), 256, 0, stream>>>(attnOutF, layerInF,
                                          b_bias_1 + m * 512, b_scale_1 + m * 512,
                                          x1F, x1H, x1L, -1);
    gemm_bt<true><<<dim3(FFN / 128, 16), 256, 0, stream>>>(x1H, x1L, Wff1H + of, Wff1L + of,
                                                           b_ff1 + m * FFN, nullptr, hBH, hBL,
                                                           512, FFN);
    gemm_bt<false><<<dim3(4, 16), 256, 0, stream>>>(hBH, hBL, Wff2H + of, Wff2L + of,
                                                    b_ff2 + m * 512, attnOutF, nullptr, nullptr,
                                                    FFN, 512);
    ln_res<<<dim3(512), 256, 0, stream>>>(attnOutF, x1F,
                                          b_bias_2 + m * 512, b_scale_2 + m * 512,
                                          layerInF, nullptr, nullptr, -1);
    curX = layerInF;
  }
  ln_res<<<dim3(512), 256, 0, stream>>>(curX, decIn, d_o_bias, d_o_scale,
                                        nullptr, decOutH, decOutL, -1);
  gemm_bt<false><<<dim3(VOCAB / 128, 16), 256, 0, stream>>>(decOutH, decOutL, WoutH, WoutL,
                                                            nullptr, out, nullptr, nullptr,
                                                            512, VOCAB);
}